// Round 2
// baseline (201.357 us; speedup 1.0000x reference)
//
#include <hip/hip_runtime.h>
#include <hip/hip_bf16.h>
#include <math.h>

// Problem constants (reference: x of shape (8, 2048, 2048) fp32; pe depends
// only on the shape). emb_dim = H (second-to-last dim).
#define PE_B 8
#define PE_H 2048
#define PE_W 2048

// ---------------------------------------------------------------------------
// Kernel 1: w_k table. w_k[j] = 10000^(-2 j / H), computed in double and
// rounded once to f32 (correctly-rounded vs reference's f32 powf to ~1 ulp).
// 2048 threads, runs in ~2 us, negligible.
// ---------------------------------------------------------------------------
__global__ void pe_wk_table_kernel(float* __restrict__ wk) {
    int j = blockIdx.x * blockDim.x + threadIdx.x;
    if (j < PE_W) {
        double e = -2.0 * (double)j / (double)PE_H;
        wk[j] = (float)pow(10000.0, e);
    }
}

// ---------------------------------------------------------------------------
// Kernel 2: fill pe. One thread = one row x 4 consecutive cols (one float4),
// stored to all 8 batch copies (8 x 16B stores = 128 B per 4 trig ops).
// Cols 4c+0..3 alternate parity -> sin, cos, sin, cos.
// Grid: (2048*2048/4)/256 = 4096 blocks of 256.
// ---------------------------------------------------------------------------
__global__ __launch_bounds__(256) void pe_fill_kernel(
        const float* __restrict__ wk, float* __restrict__ out) {
    const int v = blockIdx.x * blockDim.x + threadIdx.x;  // 0 .. H*W/4-1
    const int row = v >> 9;          // W/4 = 512 quads per row
    const int c4  = v & 511;         // quad index within row

    const float rowf = (float)row;
    const float4 wk4 = reinterpret_cast<const float4*>(wk)[c4];

    float4 r;
    r.x = sinf(rowf * wk4.x);   // col 4c+0 (even)
    r.y = cosf(rowf * wk4.y);   // col 4c+1 (odd)
    r.z = sinf(rowf * wk4.z);   // col 4c+2 (even)
    r.w = cosf(rowf * wk4.w);   // col 4c+3 (odd)

    float4* __restrict__ out4 = reinterpret_cast<float4*>(out);
    const int plane4 = (PE_H * PE_W) >> 2;   // 1048576 float4s per batch image
#pragma unroll
    for (int b = 0; b < PE_B; ++b) {
        out4[b * plane4 + v] = r;
    }
}

extern "C" void kernel_launch(void* const* d_in, const int* in_sizes, int n_in,
                              void* d_out, int out_size, void* d_ws, size_t ws_size,
                              hipStream_t stream) {
    (void)d_in; (void)in_sizes; (void)n_in; (void)out_size; (void)ws_size;

    float* wk  = (float*)d_ws;          // 2048 floats = 8 KB of workspace
    float* out = (float*)d_out;

    // 1) build the w_k column table (d_ws is re-poisoned before every launch,
    //    so this must run every call — it does).
    pe_wk_table_kernel<<<(PE_W + 255) / 256, 256, 0, stream>>>(wk);

    // 2) fill all 8*2048*2048 outputs.
    const int quads = (PE_H * PE_W) / 4;          // 1,048,576
    pe_fill_kernel<<<quads / 256, 256, 0, stream>>>(wk, out);
}

// Round 3
// 199.684 us; speedup vs baseline: 1.0084x; 1.0084x over previous
//
#include <hip/hip_runtime.h>
#include <hip/hip_bf16.h>
#include <math.h>

// Output-only op: pe depends ONLY on the shape (8, 2048, 2048) fp32.
// emb_dim = H = 2048. Roofline = pure HBM write: 134.2 MB / ~6.5 TB/s ~= 21 us.
#define PE_B 8
#define PE_H 2048
#define PE_W 2048

// Single kernel. One thread = one row x 4 consecutive cols (one float4),
// computed once and stored to all 8 batch copies (8 x 16B = 128 B stored
// per 4 trig ops -> trivially memory-bound).
//
// w_k[j] = 10000^(-2 j / H) = exp2(-j * c), c = log2(10000)/1024.
// Dekker-split constant: C_HI = 6803/2^19 has a 13-bit mantissa, j has <= 11
// bits, so jf*C_HI is EXACT in f32 (13+11 = 24-bit product, 2047*6803 < 2^24).
// t = fmaf(jf, C_LO, jf*C_HI) then carries <= 0.5 ulp error -> relative w_k
// error ~6e-7 -> worst-case sin/cos delta ~1e-4 (row-amplified), well under
// the 3.9e-3 divergence already present from the reference's own f32 pow.
__global__ __launch_bounds__(256) void pe_fill_kernel(float* __restrict__ out) {
    const int v   = blockIdx.x * blockDim.x + threadIdx.x;  // 0 .. H*W/4-1
    const int row = v >> 9;             // W/4 = 512 quads per row
    const int c0  = (v & 511) << 2;     // first column of this quad (even)

    const float C_HI = 6803.0f / 524288.0f;   // 0.0129756927490234375 (exact*j)
    const float C_LO = 5.8887163e-7f;         // log2(10000)/1024 - C_HI

    const float rowf = (float)row;

    float4 r;
    {   // col c0+0: even -> sin
        const float jf = (float)(c0 + 0);
        const float wk = exp2f(-fmaf(jf, C_LO, jf * C_HI));
        r.x = sinf(rowf * wk);
    }
    {   // col c0+1: odd -> cos
        const float jf = (float)(c0 + 1);
        const float wk = exp2f(-fmaf(jf, C_LO, jf * C_HI));
        r.y = cosf(rowf * wk);
    }
    {   // col c0+2: even -> sin
        const float jf = (float)(c0 + 2);
        const float wk = exp2f(-fmaf(jf, C_LO, jf * C_HI));
        r.z = sinf(rowf * wk);
    }
    {   // col c0+3: odd -> cos
        const float jf = (float)(c0 + 3);
        const float wk = exp2f(-fmaf(jf, C_LO, jf * C_HI));
        r.w = cosf(rowf * wk);
    }

    float4* __restrict__ out4 = reinterpret_cast<float4*>(out);
    const int plane4 = (PE_H * PE_W) >> 2;   // 1,048,576 float4s per image
#pragma unroll
    for (int b = 0; b < PE_B; ++b) {
        out4[b * plane4 + v] = r;
    }
}

extern "C" void kernel_launch(void* const* d_in, const int* in_sizes, int n_in,
                              void* d_out, int out_size, void* d_ws, size_t ws_size,
                              hipStream_t stream) {
    (void)d_in; (void)in_sizes; (void)n_in; (void)out_size;
    (void)d_ws; (void)ws_size;

    float* out = (float*)d_out;
    const int quads = (PE_H * PE_W) / 4;     // 1,048,576 threads
    pe_fill_kernel<<<quads / 256, 256, 0, stream>>>(out);
}